// Round 2
// baseline (212.901 us; speedup 1.0000x reference)
//
#include <hip/hip_runtime.h>

// E = sum over 4 directional diffs squared of avgpool4(mean_c(org - enhance)).
// Kernel 1: p[b,py,px] = (1/48) * sum over 3 channels, 4x4 window of (org-enh).
//   Each thread owns one pooled pixel; the 4x4 window columns are exactly one
//   float4 of a 512-wide row. Loads are batched 8-at-a-time (4 org + 4 enh per
//   channel) into independent temporaries with 4 independent accumulators so
//   the scheduler keeps many 1 KiB/wave loads in flight (R0 had VGPR=16 and
//   ~2 loads in flight -> 2.8 TB/s; this targets the 6.3 TB/s ceiling).
// Kernel 2: 5-point stencil on p (2 MB, L2-resident), writes E.

__global__ __launch_bounds__(256) void pool_diff_kernel(
    const float4* __restrict__ org, const float4* __restrict__ enh,
    float* __restrict__ p) {
  int idx = blockIdx.x * 256 + threadIdx.x;   // = b*16384 + py*128 + px
  int px = idx & 127;
  int py = (idx >> 7) & 127;
  int b  = idx >> 14;
  // float4 units: each 512-float row is 128 float4s; channel stride 512*128.
  int base = b * 3 * 512 * 128 + py * 4 * 128 + px;

  float4 s0 = {0.f, 0.f, 0.f, 0.f};
  float4 s1 = {0.f, 0.f, 0.f, 0.f};
  float4 s2 = {0.f, 0.f, 0.f, 0.f};
  float4 s3 = {0.f, 0.f, 0.f, 0.f};

#pragma unroll
  for (int c = 0; c < 3; ++c) {
    int off = base + c * (512 * 128);
    // 8 independent loads issued before any use.
    float4 o0 = org[off +   0];
    float4 o1 = org[off + 128];
    float4 o2 = org[off + 256];
    float4 o3 = org[off + 384];
    float4 e0 = enh[off +   0];
    float4 e1 = enh[off + 128];
    float4 e2 = enh[off + 256];
    float4 e3 = enh[off + 384];
    s0.x += o0.x - e0.x; s0.y += o0.y - e0.y; s0.z += o0.z - e0.z; s0.w += o0.w - e0.w;
    s1.x += o1.x - e1.x; s1.y += o1.y - e1.y; s1.z += o1.z - e1.z; s1.w += o1.w - e1.w;
    s2.x += o2.x - e2.x; s2.y += o2.y - e2.y; s2.z += o2.z - e2.z; s2.w += o2.w - e2.w;
    s3.x += o3.x - e3.x; s3.y += o3.y - e3.y; s3.z += o3.z - e3.z; s3.w += o3.w - e3.w;
  }

  float sum = (s0.x + s0.y + s0.z + s0.w) + (s1.x + s1.y + s1.z + s1.w) +
              (s2.x + s2.y + s2.z + s2.w) + (s3.x + s3.y + s3.z + s3.w);
  p[idx] = sum * (1.0f / 48.0f);
}

__global__ __launch_bounds__(256) void espa_stencil_kernel(
    const float* __restrict__ p, float* __restrict__ out) {
  int idx = blockIdx.x * 256 + threadIdx.x;   // = b*16384 + y*128 + x
  int x = idx & 127;
  int y = (idx >> 7) & 127;
  float c = p[idx];
  float l = (x > 0)   ? p[idx - 1]   : 0.f;
  float r = (x < 127) ? p[idx + 1]   : 0.f;
  float u = (y > 0)   ? p[idx - 128] : 0.f;
  float d = (y < 127) ? p[idx + 128] : 0.f;
  float dl = c - l, dr = c - r, du = c - u, dd = c - d;
  out[idx] = dl * dl + dr * dr + du * du + dd * dd;
}

extern "C" void kernel_launch(void* const* d_in, const int* in_sizes, int n_in,
                              void* d_out, int out_size, void* d_ws, size_t ws_size,
                              hipStream_t stream) {
  const float4* org = (const float4*)d_in[0];
  const float4* enh = (const float4*)d_in[1];
  float* p   = (float*)d_ws;       // 32*128*128 floats = 2 MB scratch
  float* out = (float*)d_out;      // 32*1*128*128 floats

  const int N = 32 * 128 * 128;    // 524288 pooled pixels
  pool_diff_kernel<<<N / 256, 256, 0, stream>>>(org, enh, p);
  espa_stencil_kernel<<<N / 256, 256, 0, stream>>>(p, out);
}

// Round 4
// 210.574 us; speedup vs baseline: 1.0111x; 1.0111x over previous
//
#include <hip/hip_runtime.h>

// E = sum over 4 directional diffs squared of avgpool4(mean_c(org - enhance)).
// Kernel 1: one block per (b, py) pooled-row strip.
//   Strip = 3 channels x 4 rows x 512 floats per array. In float4 units:
//   channel stride = 512*128 = 65536 (R2 bug: used 16384), strip base =
//   b*196608 + py*512. Thread t loads float4 j=t (rows dy=0,1) and j=t+256
//   (rows dy=2,3) of each channel substrip — contiguous 4 KiB runs per batch
//   per channel per array -> long linear wave reads. t<128 owns (dy=0,px=t)+
//   (dy=2,px=t); t>=128 owns (dy=1,px)+(dy=3,px). One LDS exchange combines.
//   Grid = 4096 blocks (16/CU, two generations) so retiring blocks backfill.
// Kernel 2: 5-point stencil on p (2 MB, L2-resident), writes E.

__global__ __launch_bounds__(256) void pool_diff_kernel(
    const float4* __restrict__ org, const float4* __restrict__ enh,
    float* __restrict__ p) {
  __shared__ float red[128];
  int t = threadIdx.x;
  int s = blockIdx.x;              // strip id = b*128 + py
  int b = s >> 7;
  int py = s & 127;
  int sb = b * 196608 + py * 512;  // float4 units

  // Batch 1: j = t (dy = t>>7), all 3 channels, both arrays — 6 loads in flight.
  int j0 = sb + t;
  float4 A0 = org[j0];
  float4 B0 = enh[j0];
  float4 A1 = org[j0 + 65536];
  float4 B1 = enh[j0 + 65536];
  float4 A2 = org[j0 + 131072];
  float4 B2 = enh[j0 + 131072];
  float a0 = (A0.x - B0.x) + (A0.y - B0.y) + (A0.z - B0.z) + (A0.w - B0.w)
           + (A1.x - B1.x) + (A1.y - B1.y) + (A1.z - B1.z) + (A1.w - B1.w)
           + (A2.x - B2.x) + (A2.y - B2.y) + (A2.z - B2.z) + (A2.w - B2.w);

  // Batch 2: j = t + 256 (dy = 2 + (t>>7)).
  int j1 = j0 + 256;
  float4 C0 = org[j1];
  float4 D0 = enh[j1];
  float4 C1 = org[j1 + 65536];
  float4 D1 = enh[j1 + 65536];
  float4 C2 = org[j1 + 131072];
  float4 D2 = enh[j1 + 131072];
  float a1 = (C0.x - D0.x) + (C0.y - D0.y) + (C0.z - D0.z) + (C0.w - D0.w)
           + (C1.x - D1.x) + (C1.y - D1.y) + (C1.z - D1.z) + (C1.w - D1.w)
           + (C2.x - D2.x) + (C2.y - D2.y) + (C2.z - D2.z) + (C2.w - D2.w);

  float mine = a0 + a1;            // this thread's (dy pair, px) partial
  if (t >= 128) red[t - 128] = mine;
  __syncthreads();
  if (t < 128) {
    p[b * 16384 + py * 128 + t] = (mine + red[t]) * (1.0f / 48.0f);
  }
}

__global__ __launch_bounds__(256) void espa_stencil_kernel(
    const float* __restrict__ p, float* __restrict__ out) {
  int idx = blockIdx.x * 256 + threadIdx.x;   // = b*16384 + y*128 + x
  int x = idx & 127;
  int y = (idx >> 7) & 127;
  float c = p[idx];
  float l = (x > 0)   ? p[idx - 1]   : 0.f;
  float r = (x < 127) ? p[idx + 1]   : 0.f;
  float u = (y > 0)   ? p[idx - 128] : 0.f;
  float d = (y < 127) ? p[idx + 128] : 0.f;
  float dl = c - l, dr = c - r, du = c - u, dd = c - d;
  out[idx] = dl * dl + dr * dr + du * du + dd * dd;
}

extern "C" void kernel_launch(void* const* d_in, const int* in_sizes, int n_in,
                              void* d_out, int out_size, void* d_ws, size_t ws_size,
                              hipStream_t stream) {
  const float4* org = (const float4*)d_in[0];
  const float4* enh = (const float4*)d_in[1];
  float* p   = (float*)d_ws;       // 32*128*128 floats = 2 MB scratch
  float* out = (float*)d_out;      // 32*1*128*128 floats

  pool_diff_kernel<<<4096, 256, 0, stream>>>(org, enh, p);  // one block per (b,py)
  const int N = 32 * 128 * 128;
  espa_stencil_kernel<<<N / 256, 256, 0, stream>>>(p, out);
}

// Round 6
// 197.374 us; speedup vs baseline: 1.0787x; 1.0669x over previous
//
#include <hip/hip_runtime.h>

// E = sum over 4 directional diffs squared of avgpool4(mean_c(org - enhance)).
// R6 = R5 with the compile fix: __builtin_nontemporal_load requires a native
// vector type, so reads go through ext_vector_type(4) float ("f4") pointers.
// Experiment: all global reads nontemporal (`nt`) to test whether the
// 2.86 TB/s demand plateau (HBM 78% idle, invariant across R0/R1/R4 access
// structures) is a cached-read-path miss-tracking cap that streaming loads
// can dodge.

typedef float f4 __attribute__((ext_vector_type(4)));

__global__ __launch_bounds__(256) void pool_diff_kernel(
    const f4* __restrict__ org, const f4* __restrict__ enh,
    float* __restrict__ p) {
  __shared__ float red[128];
  int t = threadIdx.x;
  int s = blockIdx.x;              // strip id = b*128 + py
  int b = s >> 7;
  int py = s & 127;
  int sb = b * 196608 + py * 512;  // float4 units; channel stride 65536

  int j0 = sb + t;
  f4 A0 = __builtin_nontemporal_load(&org[j0]);
  f4 B0 = __builtin_nontemporal_load(&enh[j0]);
  f4 A1 = __builtin_nontemporal_load(&org[j0 + 65536]);
  f4 B1 = __builtin_nontemporal_load(&enh[j0 + 65536]);
  f4 A2 = __builtin_nontemporal_load(&org[j0 + 131072]);
  f4 B2 = __builtin_nontemporal_load(&enh[j0 + 131072]);
  f4 acc = (A0 - B0) + (A1 - B1) + (A2 - B2);

  int j1 = j0 + 256;
  f4 C0 = __builtin_nontemporal_load(&org[j1]);
  f4 D0 = __builtin_nontemporal_load(&enh[j1]);
  f4 C1 = __builtin_nontemporal_load(&org[j1 + 65536]);
  f4 D1 = __builtin_nontemporal_load(&enh[j1 + 65536]);
  f4 C2 = __builtin_nontemporal_load(&org[j1 + 131072]);
  f4 D2 = __builtin_nontemporal_load(&enh[j1 + 131072]);
  acc += (C0 - D0) + (C1 - D1) + (C2 - D2);

  float mine = acc.x + acc.y + acc.z + acc.w;  // (dy pair, px) partial
  if (t >= 128) red[t - 128] = mine;
  __syncthreads();
  if (t < 128) {
    p[b * 16384 + py * 128 + t] = (mine + red[t]) * (1.0f / 48.0f);
  }
}

__global__ __launch_bounds__(256) void espa_stencil_kernel(
    const float* __restrict__ p, float* __restrict__ out) {
  int idx = blockIdx.x * 256 + threadIdx.x;   // = b*16384 + y*128 + x
  int x = idx & 127;
  int y = (idx >> 7) & 127;
  float c = p[idx];
  float l = (x > 0)   ? p[idx - 1]   : 0.f;
  float r = (x < 127) ? p[idx + 1]   : 0.f;
  float u = (y > 0)   ? p[idx - 128] : 0.f;
  float d = (y < 127) ? p[idx + 128] : 0.f;
  float dl = c - l, dr = c - r, du = c - u, dd = c - d;
  out[idx] = dl * dl + dr * dr + du * du + dd * dd;
}

extern "C" void kernel_launch(void* const* d_in, const int* in_sizes, int n_in,
                              void* d_out, int out_size, void* d_ws, size_t ws_size,
                              hipStream_t stream) {
  const f4* org = (const f4*)d_in[0];
  const f4* enh = (const f4*)d_in[1];
  float* p   = (float*)d_ws;       // 32*128*128 floats = 2 MB scratch
  float* out = (float*)d_out;      // 32*1*128*128 floats

  pool_diff_kernel<<<4096, 256, 0, stream>>>(org, enh, p);  // one block per (b,py)
  const int N = 32 * 128 * 128;
  espa_stencil_kernel<<<N / 256, 256, 0, stream>>>(p, out);
}